// Round 2
// baseline (2104.664 us; speedup 1.0000x reference)
//
#include <hip/hip_runtime.h>
#include <hip/hip_bf16.h>
#include <math.h>

// Problem constants
#define B_  4
#define N_  2048
#define DIM_ 512
#define HEADS_ 8
#define DHEAD_ 64
#define QKV_ 1536        // 3*512
#define MASK_C 1e-8f

// Clamp for exp args (args are always <= 0; clamp only guards inf corner cases)
__device__ __forceinline__ float expc(float a) { return expf(fmaxf(a, -80.0f)); }

// ---------------------------------------------------------------------------
// Kernel 1: LayerNorm. One block (256 threads) per row of 512. fp32 in/out.
// ---------------------------------------------------------------------------
__global__ __launch_bounds__(256) void ln_kernel(const float* __restrict__ x,
                                                 const float* __restrict__ gamma,
                                                 const float* __restrict__ beta,
                                                 float* __restrict__ h) {
    int row = blockIdx.x;                 // 0..8191  (b*N+n)
    int t = threadIdx.x;                  // 0..255
    const float* xr = x + (size_t)row * DIM_;
    float e0 = xr[t];
    float e1 = xr[t + 256];
    float s  = e0 + e1;
    float sq = e0 * e0 + e1 * e1;
    for (int off = 32; off; off >>= 1) {
        s  += __shfl_xor(s, off);
        sq += __shfl_xor(sq, off);
    }
    __shared__ float red[8];
    int w = t >> 6, lane = t & 63;
    if (lane == 0) { red[w] = s; red[4 + w] = sq; }
    __syncthreads();
    float S  = red[0] + red[1] + red[2] + red[3];
    float SQ = red[4] + red[5] + red[6] + red[7];
    float mu = S * (1.0f / DIM_);
    float var = SQ * (1.0f / DIM_) - mu * mu;
    float rs = rsqrtf(var + 1e-5f);
    float* hr = h + (size_t)row * DIM_;
    hr[t]       = (e0 - mu) * rs * gamma[t] + beta[t];
    hr[t + 256] = (e1 - mu) * rs * gamma[t + 256] + beta[t + 256];
}

// ---------------------------------------------------------------------------
// Kernel 2: QKV GEMM.  C[m][n] = sum_k h[m][k] * w[n][k]
// M=8192, N=1536, K=512.  64x64 tile, BK=16, 256 threads, 4x4 microtile.
// ---------------------------------------------------------------------------
__global__ __launch_bounds__(256) void qkv_gemm(const float* __restrict__ h,
                                                const float* __restrict__ wq,
                                                float* __restrict__ qkv) {
    __shared__ __align__(16) float As[16][68];
    __shared__ __align__(16) float Bs[16][68];
    int bm = blockIdx.x % 128;            // M tiles
    int bn = blockIdx.x / 128;            // N tiles (24)
    int t  = threadIdx.x;
    int tx = t % 16, ty = t / 16;         // tx -> n, ty -> m
    float acc[4][4] = {};
    for (int k0 = 0; k0 < 512; k0 += 16) {
        __syncthreads();
        #pragma unroll
        for (int r = 0; r < 4; r++) {
            int flat = t + 256 * r;       // 0..1023
            int m = flat >> 4, k = flat & 15;
            As[k][m] = h[(size_t)(bm * 64 + m) * 512 + k0 + k];
            Bs[k][m] = wq[(size_t)(bn * 64 + m) * 512 + k0 + k];
        }
        __syncthreads();
        #pragma unroll
        for (int kk = 0; kk < 16; kk++) {
            float4 a4 = *(const float4*)&As[kk][ty * 4];
            float4 b4 = *(const float4*)&Bs[kk][tx * 4];
            float av[4] = {a4.x, a4.y, a4.z, a4.w};
            float bv[4] = {b4.x, b4.y, b4.z, b4.w};
            #pragma unroll
            for (int i = 0; i < 4; i++)
                #pragma unroll
                for (int j = 0; j < 4; j++)
                    acc[i][j] += av[i] * bv[j];
        }
    }
    #pragma unroll
    for (int i = 0; i < 4; i++) {
        int m = bm * 64 + ty * 4 + i;
        #pragma unroll
        for (int j = 0; j < 4; j++) {
            int n = bn * 64 + tx * 4 + j;
            qkv[(size_t)m * QKV_ + n] = acc[i][j];
        }
    }
}

// ---------------------------------------------------------------------------
// Kernel 3: suffix sums of V at 64-row tile boundaries.
// suff[bh][t][d] = sum_{m >= 64*t} v[bh][m][d],  t = 0..32
// ---------------------------------------------------------------------------
__global__ void vsuff_kernel(const float* __restrict__ qkv,
                             float* __restrict__ suff) {
    int bh = blockIdx.x;                  // 0..31
    int b = bh >> 3, head = bh & 7;
    int d = threadIdx.x;                  // 0..63
    float S = 0.0f;
    suff[((size_t)bh * 33 + 32) * 64 + d] = 0.0f;
    for (int tt = 31; tt >= 0; tt--) {
        for (int mm = 0; mm < 64; mm++) {
            int m = tt * 64 + mm;
            S += qkv[((size_t)(b * N_ + m)) * QKV_ + 1024 + head * 64 + d];
        }
        suff[((size_t)bh * 33 + tt) * 64 + d] = S;
    }
}

// ---------------------------------------------------------------------------
// Kernel 4: causal attention with masked-fill=1e-8 semantics.
// Block = 256 threads = 4 waves; wave w handles query row rtile*4+w.
// Lane j = key j of current tile for scores; lane d = output dim for acc.
// ---------------------------------------------------------------------------
__global__ __launch_bounds__(256) void attn_kernel(const float* __restrict__ qkv,
                                                   const float* __restrict__ suff,
                                                   float* __restrict__ out) {
    __shared__ __align__(16) float q_s[4][64];
    __shared__ __align__(16) float k_s[64][68];
    __shared__ __align__(16) float v_s[64][68];
    int blk = blockIdx.x;
    int rtile = blk % (N_ / 4);           // 0..511
    int bh = blk / (N_ / 4);              // 0..31
    int b = bh >> 3, head = bh & 7;
    int t = threadIdx.x;
    int w = t >> 6, lane = t & 63;

    {
        int row = rtile * 4 + w;
        q_s[w][lane] = qkv[((size_t)(b * N_ + row)) * QKV_ + head * 64 + lane];
    }

    int i = rtile * 4 + w;
    int n_tiles = (rtile >> 4) + 1;       // tiles covering m <= i_max of block
    float M = -3.0e38f, L = 0.0f, acc = 0.0f;

    for (int jt = 0; jt < n_tiles; jt++) {
        __syncthreads();
        #pragma unroll
        for (int r = 0; r < 16; r++) {
            int flat = t + 256 * r;       // 0..4095
            int m = flat >> 6, d = flat & 63;
            const float* base = &qkv[((size_t)(b * N_ + jt * 64 + m)) * QKV_ + head * 64 + d];
            k_s[m][d] = base[512];
            v_s[m][d] = base[1024];
        }
        __syncthreads();

        int m_idx = jt * 64 + lane;
        float s;
        if (m_idx <= i) {
            s = 0.0f;
            #pragma unroll
            for (int dd = 0; dd < 16; dd++) {
                float4 qv = *(const float4*)&q_s[w][dd * 4];
                float4 kv = *(const float4*)&k_s[lane][dd * 4];
                s += qv.x * kv.x + qv.y * kv.y + qv.z * kv.z + qv.w * kv.w;
            }
        } else {
            s = MASK_C;                   // faithful: masked logit is 1e-8
        }
        float tm = s;
        for (int off = 32; off; off >>= 1) tm = fmaxf(tm, __shfl_xor(tm, off));
        float Mn = fmaxf(M, tm);
        float alpha = expc(M - Mn);       // first tile: L=acc=0, value irrelevant
        float p = expc(s - Mn);
        float ps = p;
        for (int off = 32; off; off >>= 1) ps += __shfl_xor(ps, off);
        L = L * alpha + ps;
        acc *= alpha;
        #pragma unroll 8
        for (int j = 0; j < 64; j++) {
            float pj = __shfl(p, j);
            acc += pj * v_s[j][lane];
        }
        M = Mn;
    }

    // tail: columns [T_end, N) all have logit 1e-8
    int T_end = n_tiles * 64;
    int cnt = N_ - T_end;
    if (cnt > 0) {
        float Mc = fmaxf(M, MASK_C);
        float al = expc(M - Mc);
        float pc = expc(MASK_C - Mc);
        L = L * al + pc * (float)cnt;
        acc = acc * al + pc * suff[((size_t)bh * 33 + n_tiles) * 64 + lane];
    }

    out[((size_t)(b * N_ + i)) * DIM_ + head * 64 + lane] = acc / L;
}

// ---------------------------------------------------------------------------
extern "C" void kernel_launch(void* const* d_in, const int* in_sizes, int n_in,
                              void* d_out, int out_size, void* d_ws, size_t ws_size,
                              hipStream_t stream) {
    const float* x     = (const float*)d_in[0];
    const float* gamma = (const float*)d_in[1];
    const float* beta  = (const float*)d_in[2];
    const float* w_qkv = (const float*)d_in[3];
    // d_in[4] is the causal mask: deterministically tril, hardcoded in kernel.
    float* out = (float*)d_out;

    float* h    = (float*)d_ws;                       // 8192*512
    float* qkv  = h + (size_t)8192 * 512;             // 8192*1536
    float* suff = qkv + (size_t)8192 * 1536;          // 32*33*64

    ln_kernel<<<B_ * N_, 256, 0, stream>>>(x, gamma, beta, h);
    qkv_gemm<<<128 * 24, 256, 0, stream>>>(h, w_qkv, qkv);
    vsuff_kernel<<<B_ * HEADS_, 64, 0, stream>>>(qkv, suff);
    attn_kernel<<<B_ * HEADS_ * (N_ / 4), 256, 0, stream>>>(qkv, suff, out);
}

// Round 3
// 586.202 us; speedup vs baseline: 3.5903x; 3.5903x over previous
//
#include <hip/hip_runtime.h>
#include <hip/hip_bf16.h>
#include <math.h>

// Problem constants
#define B_  4
#define N_  2048
#define DIM_ 512
#define HEADS_ 8
#define DHEAD_ 64
#define QKV_ 1536        // 3*512
#define MASK_C 1e-8f

// Clamp for exp args (args are always <= 0; clamp only guards inf corner cases)
__device__ __forceinline__ float expc(float a) { return expf(fmaxf(a, -80.0f)); }

// ---------------------------------------------------------------------------
// Kernel 1: LayerNorm. One block (256 threads) per row of 512. fp32 in/out.
// ---------------------------------------------------------------------------
__global__ __launch_bounds__(256) void ln_kernel(const float* __restrict__ x,
                                                 const float* __restrict__ gamma,
                                                 const float* __restrict__ beta,
                                                 float* __restrict__ h) {
    int row = blockIdx.x;
    int t = threadIdx.x;
    const float* xr = x + (size_t)row * DIM_;
    float e0 = xr[t];
    float e1 = xr[t + 256];
    float s  = e0 + e1;
    float sq = e0 * e0 + e1 * e1;
    for (int off = 32; off; off >>= 1) {
        s  += __shfl_xor(s, off);
        sq += __shfl_xor(sq, off);
    }
    __shared__ float red[8];
    int w = t >> 6, lane = t & 63;
    if (lane == 0) { red[w] = s; red[4 + w] = sq; }
    __syncthreads();
    float S  = red[0] + red[1] + red[2] + red[3];
    float SQ = red[4] + red[5] + red[6] + red[7];
    float mu = S * (1.0f / DIM_);
    float var = SQ * (1.0f / DIM_) - mu * mu;
    float rs = rsqrtf(var + 1e-5f);
    float* hr = h + (size_t)row * DIM_;
    hr[t]       = (e0 - mu) * rs * gamma[t] + beta[t];
    hr[t + 256] = (e1 - mu) * rs * gamma[t + 256] + beta[t + 256];
}

// ---------------------------------------------------------------------------
// Kernel 2: QKV GEMM.  C[m][n] = sum_k h[m][k] * w[n][k]
// M=8192, N=1536, K=512.  64x64 tile, BK=16, 256 threads, 4x4 microtile.
// ---------------------------------------------------------------------------
__global__ __launch_bounds__(256) void qkv_gemm(const float* __restrict__ h,
                                                const float* __restrict__ wq,
                                                float* __restrict__ qkv) {
    __shared__ __align__(16) float As[16][68];
    __shared__ __align__(16) float Bs[16][68];
    int bm = blockIdx.x % 128;
    int bn = blockIdx.x / 128;
    int t  = threadIdx.x;
    int tx = t % 16, ty = t / 16;
    float acc[4][4] = {};
    for (int k0 = 0; k0 < 512; k0 += 16) {
        __syncthreads();
        #pragma unroll
        for (int r = 0; r < 4; r++) {
            int flat = t + 256 * r;
            int m = flat >> 4, k = flat & 15;
            As[k][m] = h[(size_t)(bm * 64 + m) * 512 + k0 + k];
            Bs[k][m] = wq[(size_t)(bn * 64 + m) * 512 + k0 + k];
        }
        __syncthreads();
        #pragma unroll
        for (int kk = 0; kk < 16; kk++) {
            float4 a4 = *(const float4*)&As[kk][ty * 4];
            float4 b4 = *(const float4*)&Bs[kk][tx * 4];
            float av[4] = {a4.x, a4.y, a4.z, a4.w};
            float bv[4] = {b4.x, b4.y, b4.z, b4.w};
            #pragma unroll
            for (int i = 0; i < 4; i++)
                #pragma unroll
                for (int j = 0; j < 4; j++)
                    acc[i][j] += av[i] * bv[j];
        }
    }
    #pragma unroll
    for (int i = 0; i < 4; i++) {
        int m = bm * 64 + ty * 4 + i;
        #pragma unroll
        for (int j = 0; j < 4; j++) {
            int n = bn * 64 + tx * 4 + j;
            qkv[(size_t)m * QKV_ + n] = acc[i][j];
        }
    }
}

// ---------------------------------------------------------------------------
// Kernel 3a: per-tile partial sums of V.  part[bh][tt][d] = sum of 64 rows.
// ---------------------------------------------------------------------------
__global__ void vpart_kernel(const float* __restrict__ qkv,
                             float* __restrict__ part) {
    int blk = blockIdx.x;                 // 0..1023
    int bh = blk >> 5, tt = blk & 31;
    int b = bh >> 3, head = bh & 7;
    int d = threadIdx.x;                  // 0..63
    float S = 0.0f;
    #pragma unroll 8
    for (int mm = 0; mm < 64; mm++) {
        int m = tt * 64 + mm;
        S += qkv[((size_t)(b * N_ + m)) * QKV_ + 1024 + head * 64 + d];
    }
    part[((size_t)(bh * 32 + tt)) * 64 + d] = S;
}

// ---------------------------------------------------------------------------
// Kernel 3b: suffix scan.  suff[bh][t][d] = sum_{tt >= t} part[bh][tt][d]
// ---------------------------------------------------------------------------
__global__ void vscan_kernel(const float* __restrict__ part,
                             float* __restrict__ suff) {
    int bh = blockIdx.x;                  // 0..31
    int d = threadIdx.x;                  // 0..63
    float S = 0.0f;
    suff[((size_t)bh * 33 + 32) * 64 + d] = 0.0f;
    for (int tt = 31; tt >= 0; tt--) {
        S += part[((size_t)(bh * 32 + tt)) * 64 + d];
        suff[((size_t)bh * 33 + tt) * 64 + d] = S;
    }
}

// ---------------------------------------------------------------------------
// Kernel 4: causal attention, masked-fill=1e-8 semantics.
// Block = 64 query rows x full head. 256 threads, 4x4 microtile GEMMs.
// ---------------------------------------------------------------------------
__global__ __launch_bounds__(256) void attn_kernel(const float* __restrict__ qkv,
                                                   const float* __restrict__ suff,
                                                   float* __restrict__ out) {
    __shared__ __align__(16) float Qs[64][68];   // k-major: Qs[d][i]
    __shared__ __align__(16) float Ks[64][68];   // k-major: Ks[d][j]; reused as Ps[j][i]
    __shared__ __align__(16) float Vs[64][68];   // row-major: Vs[j][d]
    int blk = blockIdx.x;
    int bh = blk & 31;                    // interleave bh fastest
    int rt = 31 - (blk >> 5);             // longest blocks dispatched first
    int b = bh >> 3, head = bh & 7;
    int t = threadIdx.x;
    int tx = t & 15, ty = t >> 4;         // tx -> j/dim group, ty -> i group

    // stage Q transposed: Qs[d][i]
    #pragma unroll
    for (int r = 0; r < 16; r++) {
        int f = t + 256 * r;
        int d = f & 63, i = f >> 6;
        Qs[d][i] = qkv[((size_t)(b * N_ + rt * 64 + i)) * QKV_ + head * 64 + d];
    }

    float O[4][4] = {};
    float M[4], L[4];
    #pragma unroll
    for (int a = 0; a < 4; a++) { M[a] = -3.0e38f; L[a] = 0.0f; }

    for (int jt = 0; jt <= rt; jt++) {
        __syncthreads();                  // done with previous Ps/Vs
        #pragma unroll
        for (int r = 0; r < 16; r++) {
            int f = t + 256 * r;
            int d = f & 63, j = f >> 6;
            const float* base = &qkv[((size_t)(b * N_ + jt * 64 + j)) * QKV_ + head * 64 + d];
            Ks[d][j] = base[512];
            Vs[j][d] = base[1024];
        }
        __syncthreads();

        // S = Q K^T (outer product over d)
        float S[4][4] = {};
        #pragma unroll 8
        for (int kk = 0; kk < 64; kk++) {
            float4 qv = *(const float4*)&Qs[kk][ty * 4];
            float4 kv = *(const float4*)&Ks[kk][tx * 4];
            float av[4] = {qv.x, qv.y, qv.z, qv.w};
            float bv[4] = {kv.x, kv.y, kv.z, kv.w};
            #pragma unroll
            for (int a = 0; a < 4; a++)
                #pragma unroll
                for (int bb = 0; bb < 4; bb++)
                    S[a][bb] += av[a] * bv[bb];
        }

        // diagonal-tile causal mask: logit := 1e-8 where j > i
        if (jt == rt) {
            #pragma unroll
            for (int a = 0; a < 4; a++)
                #pragma unroll
                for (int bb = 0; bb < 4; bb++)
                    if (tx * 4 + bb > ty * 4 + a) S[a][bb] = MASK_C;
        }

        // online softmax per row (rows replicated across the 16 tx lanes)
        float P[4][4];
        #pragma unroll
        for (int a = 0; a < 4; a++) {
            float rm = fmaxf(fmaxf(S[a][0], S[a][1]), fmaxf(S[a][2], S[a][3]));
            #pragma unroll
            for (int off = 1; off < 16; off <<= 1) rm = fmaxf(rm, __shfl_xor(rm, off));
            float Mn = fmaxf(M[a], rm);
            float alpha = expc(M[a] - Mn);
            float rs = 0.0f;
            #pragma unroll
            for (int bb = 0; bb < 4; bb++) {
                P[a][bb] = expc(S[a][bb] - Mn);
                rs += P[a][bb];
            }
            #pragma unroll
            for (int off = 1; off < 16; off <<= 1) rs += __shfl_xor(rs, off);
            L[a] = L[a] * alpha + rs;
            M[a] = Mn;
            #pragma unroll
            for (int cc = 0; cc < 4; cc++) O[a][cc] *= alpha;
        }

        __syncthreads();                  // everyone done reading Ks as K
        // write P transposed into Ks buffer: Ps[j][i]
        #pragma unroll
        for (int bb = 0; bb < 4; bb++) {
            float4 pv = make_float4(P[0][bb], P[1][bb], P[2][bb], P[3][bb]);
            *(float4*)&Ks[tx * 4 + bb][ty * 4] = pv;
        }
        __syncthreads();

        // O += P V (outer product over j)
        #pragma unroll 8
        for (int kk = 0; kk < 64; kk++) {
            float4 pv = *(const float4*)&Ks[kk][ty * 4];
            float4 vv = *(const float4*)&Vs[kk][tx * 4];
            float av[4] = {pv.x, pv.y, pv.z, pv.w};
            float bv[4] = {vv.x, vv.y, vv.z, vv.w};
            #pragma unroll
            for (int a = 0; a < 4; a++)
                #pragma unroll
                for (int cc = 0; cc < 4; cc++)
                    O[a][cc] += av[a] * bv[cc];
        }
    }

    // tail: columns [(rt+1)*64, N) all carry logit 1e-8
    int cnt = N_ - (rt + 1) * 64;
    if (cnt > 0) {
        float4 s4 = *(const float4*)&suff[((size_t)bh * 33 + rt + 1) * 64 + tx * 4];
        float sb[4] = {s4.x, s4.y, s4.z, s4.w};
        #pragma unroll
        for (int a = 0; a < 4; a++) {
            float Mc = fmaxf(M[a], MASK_C);
            float al = expc(M[a] - Mc);
            float pc = expc(MASK_C - Mc);
            L[a] = L[a] * al + pc * (float)cnt;
            #pragma unroll
            for (int cc = 0; cc < 4; cc++) O[a][cc] = O[a][cc] * al + pc * sb[cc];
        }
    }

    #pragma unroll
    for (int a = 0; a < 4; a++) {
        float rl = 1.0f / L[a];
        int row = rt * 64 + ty * 4 + a;
        float4 o4 = make_float4(O[a][0] * rl, O[a][1] * rl, O[a][2] * rl, O[a][3] * rl);
        *(float4*)&out[((size_t)(b * N_ + row)) * DIM_ + head * 64 + tx * 4] = o4;
    }
}

// ---------------------------------------------------------------------------
extern "C" void kernel_launch(void* const* d_in, const int* in_sizes, int n_in,
                              void* d_out, int out_size, void* d_ws, size_t ws_size,
                              hipStream_t stream) {
    const float* x     = (const float*)d_in[0];
    const float* gamma = (const float*)d_in[1];
    const float* beta  = (const float*)d_in[2];
    const float* w_qkv = (const float*)d_in[3];
    // d_in[4] is the causal mask: deterministically tril, hardcoded in kernel.
    float* out = (float*)d_out;

    float* h    = (float*)d_ws;                       // 8192*512
    float* qkv  = h + (size_t)8192 * 512;             // 8192*1536
    float* part = qkv + (size_t)8192 * 1536;          // 32*32*64
    float* suff = part + (size_t)32 * 32 * 64;        // 32*33*64

    ln_kernel<<<B_ * N_, 256, 0, stream>>>(x, gamma, beta, h);
    qkv_gemm<<<128 * 24, 256, 0, stream>>>(h, w_qkv, qkv);
    vpart_kernel<<<1024, 64, 0, stream>>>(qkv, part);
    vscan_kernel<<<32, 64, 0, stream>>>(part, suff);
    attn_kernel<<<32 * 32, 256, 0, stream>>>(qkv, suff, out);
}

// Round 4
// 306.231 us; speedup vs baseline: 6.8728x; 1.9142x over previous
//
#include <hip/hip_runtime.h>
#include <hip/hip_bf16.h>
#include <math.h>

// Problem constants
#define B_  4
#define N_  2048
#define DIM_ 512
#define HEADS_ 8
#define QKV_ 1536
#define MASK_C 1e-8f

typedef __bf16 bf16_t;
typedef bf16_t bf16x8 __attribute__((ext_vector_type(8)));
typedef float  f32x4  __attribute__((ext_vector_type(4)));

__device__ __forceinline__ float expc(float a) { return expf(fmaxf(a, -80.0f)); }
__device__ __forceinline__ bf16_t f2b(float x) { return (bf16_t)x; }
__device__ __forceinline__ float  b2f(bf16_t x) { return (float)x; }

__device__ __forceinline__ f32x4 mfma16(bf16x8 a, bf16x8 b, f32x4 c) {
    return __builtin_amdgcn_mfma_f32_16x16x32_bf16(a, b, c, 0, 0, 0);
}

// ---------------------------------------------------------------------------
// Kernel 1: LayerNorm -> split bf16 (h_hi, h_lo). One block per row of 512.
// ---------------------------------------------------------------------------
__global__ __launch_bounds__(256) void ln_kernel(const float* __restrict__ x,
                                                 const float* __restrict__ gamma,
                                                 const float* __restrict__ beta,
                                                 bf16_t* __restrict__ hh,
                                                 bf16_t* __restrict__ hl) {
    int row = blockIdx.x;
    int t = threadIdx.x;
    const float* xr = x + (size_t)row * DIM_;
    float e0 = xr[t];
    float e1 = xr[t + 256];
    float s  = e0 + e1;
    float sq = e0 * e0 + e1 * e1;
    for (int off = 32; off; off >>= 1) {
        s  += __shfl_xor(s, off);
        sq += __shfl_xor(sq, off);
    }
    __shared__ float red[8];
    int w = t >> 6;
    if ((t & 63) == 0) { red[w] = s; red[4 + w] = sq; }
    __syncthreads();
    float S  = red[0] + red[1] + red[2] + red[3];
    float SQ = red[4] + red[5] + red[6] + red[7];
    float mu = S * (1.0f / DIM_);
    float var = SQ * (1.0f / DIM_) - mu * mu;
    float rs = rsqrtf(var + 1e-5f);
    float y0 = (e0 - mu) * rs * gamma[t] + beta[t];
    float y1 = (e1 - mu) * rs * gamma[t + 256] + beta[t + 256];
    size_t base = (size_t)row * DIM_;
    bf16_t h0 = f2b(y0), h1 = f2b(y1);
    hh[base + t] = h0;       hl[base + t] = f2b(y0 - b2f(h0));
    hh[base + t + 256] = h1; hl[base + t + 256] = f2b(y1 - b2f(h1));
}

// ---------------------------------------------------------------------------
// Kernel 1b: split w_qkv into bf16 hi/lo.
// ---------------------------------------------------------------------------
__global__ __launch_bounds__(256) void wsplit_kernel(const float* __restrict__ w,
                                                     bf16_t* __restrict__ wh,
                                                     bf16_t* __restrict__ wl) {
    int i = (blockIdx.x * 256 + threadIdx.x) * 4;
    float4 v = *(const float4*)&w[i];
    float vv[4] = {v.x, v.y, v.z, v.w};
    #pragma unroll
    for (int j = 0; j < 4; j++) {
        bf16_t hi = f2b(vv[j]);
        wh[i + j] = hi;
        wl[i + j] = f2b(vv[j] - b2f(hi));
    }
}

// ---------------------------------------------------------------------------
// Kernel 2: QKV GEMM via MFMA, split-bf16 3-term. C[m][n] = sum_k h[m][k] w[n][k]
// Block tile 128m x 64n, BK=64, 256 threads / 4 waves (wave: 32m x 64n).
// Epilogue re-splits to q/k (natural layout) and v (transposed [bh][d][key]).
// ---------------------------------------------------------------------------
__global__ __launch_bounds__(256) void qkv_gemm(const bf16_t* __restrict__ hh,
                                                const bf16_t* __restrict__ hl,
                                                const bf16_t* __restrict__ wh,
                                                const bf16_t* __restrict__ wl,
                                                bf16_t* __restrict__ qh, bf16_t* __restrict__ ql,
                                                bf16_t* __restrict__ kh, bf16_t* __restrict__ kl,
                                                bf16_t* __restrict__ vth, bf16_t* __restrict__ vtl) {
    __shared__ __align__(16) bf16_t Ah[128][72], Al[128][72];
    __shared__ __align__(16) bf16_t Bh[64][72],  Bl[64][72];
    int bm = blockIdx.x & 63;             // 64 m-tiles
    int bn = blockIdx.x >> 6;             // 24 n-tiles
    int t = threadIdx.x;
    int w = t >> 6, lane = t & 63, quad = lane >> 4, l16 = lane & 15;

    f32x4 acc[2][4];
    #pragma unroll
    for (int i = 0; i < 2; i++)
        #pragma unroll
        for (int j = 0; j < 4; j++) acc[i][j] = (f32x4)(0.0f);

    for (int k0 = 0; k0 < 512; k0 += 64) {
        __syncthreads();
        {   // stage A: thread t -> row t>>1, k-cols (t&1)*32 + {0,8,16,24}
            int m = t >> 1, kc = (t & 1) * 32;
            size_t g = (size_t)(bm * 128 + m) * 512 + k0 + kc;
            #pragma unroll
            for (int c = 0; c < 4; c++) {
                *(uint4*)&Ah[m][kc + 8 * c] = *(const uint4*)&hh[g + 8 * c];
                *(uint4*)&Al[m][kc + 8 * c] = *(const uint4*)&hl[g + 8 * c];
            }
            // stage B: thread t -> row t>>2, k-cols (t&3)*16 + {0,8}
            int n = t >> 2; kc = (t & 3) * 16;
            g = (size_t)(bn * 64 + n) * 512 + k0 + kc;
            #pragma unroll
            for (int c = 0; c < 2; c++) {
                *(uint4*)&Bh[n][kc + 8 * c] = *(const uint4*)&wh[g + 8 * c];
                *(uint4*)&Bl[n][kc + 8 * c] = *(const uint4*)&wl[g + 8 * c];
            }
        }
        __syncthreads();
        #pragma unroll
        for (int khf = 0; khf < 2; khf++) {
            int kb = khf * 32 + quad * 8;
            bf16x8 aH[2], aL[2];
            #pragma unroll
            for (int mt = 0; mt < 2; mt++) {
                aH[mt] = *(const bf16x8*)&Ah[w * 32 + mt * 16 + l16][kb];
                aL[mt] = *(const bf16x8*)&Al[w * 32 + mt * 16 + l16][kb];
            }
            #pragma unroll
            for (int nt = 0; nt < 4; nt++) {
                bf16x8 bH = *(const bf16x8*)&Bh[nt * 16 + l16][kb];
                bf16x8 bL = *(const bf16x8*)&Bl[nt * 16 + l16][kb];
                #pragma unroll
                for (int mt = 0; mt < 2; mt++) {
                    acc[mt][nt] = mfma16(aH[mt], bH, acc[mt][nt]);
                    acc[mt][nt] = mfma16(aH[mt], bL, acc[mt][nt]);
                    acc[mt][nt] = mfma16(aL[mt], bH, acc[mt][nt]);
                }
            }
        }
    }

    // epilogue: split & route. C/D layout: row = quad*4+reg, col = l16 (per tile)
    #pragma unroll
    for (int mt = 0; mt < 2; mt++)
        #pragma unroll
        for (int nt = 0; nt < 4; nt++)
            #pragma unroll
            for (int reg = 0; reg < 4; reg++) {
                float v = acc[mt][nt][reg];
                int row = bm * 128 + w * 32 + mt * 16 + quad * 4 + reg;
                int n = bn * 64 + nt * 16 + l16;
                bf16_t hi = f2b(v);
                bf16_t lo = f2b(v - b2f(hi));
                if (n < 512) {
                    size_t a = (size_t)row * 512 + n;
                    qh[a] = hi; ql[a] = lo;
                } else if (n < 1024) {
                    size_t a = (size_t)row * 512 + (n - 512);
                    kh[a] = hi; kl[a] = lo;
                } else {
                    int b = row >> 11, key = row & 2047;
                    int hd = (n - 1024) >> 6, d = (n - 1024) & 63;
                    size_t a = ((size_t)((b * 8 + hd) * 64 + d)) * 2048 + key;
                    vth[a] = hi; vtl[a] = lo;
                }
            }
}

// ---------------------------------------------------------------------------
// Kernel 3a/3b: V suffix sums (from split vt), for the masked-tail correction.
// ---------------------------------------------------------------------------
__global__ void vpart_kernel(const bf16_t* __restrict__ vth,
                             const bf16_t* __restrict__ vtl,
                             float* __restrict__ part) {
    int blk = blockIdx.x;                 // 0..1023
    int bh = blk >> 5, tt = blk & 31;
    int d = threadIdx.x;                  // 0..63
    size_t base = ((size_t)(bh * 64 + d)) * 2048 + tt * 64;
    float S = 0.0f;
    #pragma unroll
    for (int k = 0; k < 64; k += 8) {
        bf16x8 a = *(const bf16x8*)&vth[base + k];
        bf16x8 c = *(const bf16x8*)&vtl[base + k];
        #pragma unroll
        for (int j = 0; j < 8; j++) S += b2f(a[j]) + b2f(c[j]);
    }
    part[((size_t)(bh * 32 + tt)) * 64 + d] = S;
}

__global__ void vscan_kernel(const float* __restrict__ part,
                             float* __restrict__ suff) {
    int bh = blockIdx.x;
    int d = threadIdx.x;
    float S = 0.0f;
    suff[((size_t)bh * 33 + 32) * 64 + d] = 0.0f;
    for (int tt = 31; tt >= 0; tt--) {
        S += part[((size_t)(bh * 32 + tt)) * 64 + d];
        suff[((size_t)bh * 33 + tt) * 64 + d] = S;
    }
}

// ---------------------------------------------------------------------------
// Kernel 4: MFMA flash attention, masked-fill=1e-8 semantics, split-bf16.
// Block = 64 q-rows x one head. 4 waves; wave w owns q-rows [16w,16w+16).
// ---------------------------------------------------------------------------
__global__ __launch_bounds__(256) void attn_kernel(const bf16_t* __restrict__ qh,
                                                   const bf16_t* __restrict__ ql,
                                                   const bf16_t* __restrict__ kh,
                                                   const bf16_t* __restrict__ kl,
                                                   const bf16_t* __restrict__ vth,
                                                   const bf16_t* __restrict__ vtl,
                                                   const float* __restrict__ suff,
                                                   float* __restrict__ out) {
    __shared__ __align__(16) bf16_t Qh[64][72], Ql[64][72];
    __shared__ __align__(16) bf16_t KPh[64][72], KPl[64][72]; // K tile, then reused for P
    __shared__ __align__(16) bf16_t Vh[64][72], Vl[64][72];   // [dim][key]
    int blk = blockIdx.x;
    int bh = blk & 31;                    // interleave bh fastest
    int rt = 31 - (blk >> 5);             // longest blocks first
    int b = bh >> 3, head = bh & 7;
    int t = threadIdx.x;
    int w = t >> 6, lane = t & 63, quad = lane >> 4, l16 = lane & 15;

    {   // stage Q (split): thread t -> row t>>2, cols (t&3)*16 + {0,8}
        int r = t >> 2, c = (t & 3) * 16;
        size_t g = ((size_t)(b * N_ + rt * 64 + r)) * 512 + head * 64 + c;
        *(uint4*)&Qh[r][c]     = *(const uint4*)&qh[g];
        *(uint4*)&Qh[r][c + 8] = *(const uint4*)&qh[g + 8];
        *(uint4*)&Ql[r][c]     = *(const uint4*)&ql[g];
        *(uint4*)&Ql[r][c + 8] = *(const uint4*)&ql[g + 8];
    }

    f32x4 O[4];
    #pragma unroll
    for (int nt = 0; nt < 4; nt++) O[nt] = (f32x4)(0.0f);
    float M[4], L[4];
    #pragma unroll
    for (int r = 0; r < 4; r++) { M[r] = -3.0e38f; L[r] = 0.0f; }

    for (int jt = 0; jt <= rt; jt++) {
        __syncthreads();                  // prev iter done with KP/V buffers
        {   // stage K tile (natural) and V tile (transposed source)
            int r = t >> 2, c = (t & 3) * 16;
            size_t gk = ((size_t)(b * N_ + jt * 64 + r)) * 512 + head * 64 + c;
            *(uint4*)&KPh[r][c]     = *(const uint4*)&kh[gk];
            *(uint4*)&KPh[r][c + 8] = *(const uint4*)&kh[gk + 8];
            *(uint4*)&KPl[r][c]     = *(const uint4*)&kl[gk];
            *(uint4*)&KPl[r][c + 8] = *(const uint4*)&kl[gk + 8];
            size_t gv = ((size_t)(bh * 64 + r)) * 2048 + jt * 64 + c;  // r=dim, c=key
            *(uint4*)&Vh[r][c]      = *(const uint4*)&vth[gv];
            *(uint4*)&Vh[r][c + 8]  = *(const uint4*)&vth[gv + 8];
            *(uint4*)&Vl[r][c]      = *(const uint4*)&vtl[gv];
            *(uint4*)&Vl[r][c + 8]  = *(const uint4*)&vtl[gv + 8];
        }
        __syncthreads();

        // S = Q K^T, 3-term split
        f32x4 S[4];
        #pragma unroll
        for (int nt = 0; nt < 4; nt++) S[nt] = (f32x4)(0.0f);
        #pragma unroll
        for (int khf = 0; khf < 2; khf++) {
            int kb = khf * 32 + quad * 8;
            bf16x8 aH = *(const bf16x8*)&Qh[w * 16 + l16][kb];
            bf16x8 aL = *(const bf16x8*)&Ql[w * 16 + l16][kb];
            #pragma unroll
            for (int nt = 0; nt < 4; nt++) {
                bf16x8 bH = *(const bf16x8*)&KPh[nt * 16 + l16][kb];
                bf16x8 bL = *(const bf16x8*)&KPl[nt * 16 + l16][kb];
                S[nt] = mfma16(aH, bH, S[nt]);
                S[nt] = mfma16(aH, bL, S[nt]);
                S[nt] = mfma16(aL, bH, S[nt]);
            }
        }

        // diagonal-tile causal mask: logit := 1e-8 where col > row (local)
        if (jt == rt) {
            int lrow = w * 16 + quad * 4;
            #pragma unroll
            for (int nt = 0; nt < 4; nt++)
                #pragma unroll
                for (int reg = 0; reg < 4; reg++)
                    if (nt * 16 + l16 > lrow + reg) S[nt][reg] = MASK_C;
        }

        // online softmax per row (row = reg within quad; reduce across 16 lanes)
        float P[4][4];                    // [nt][reg]
        #pragma unroll
        for (int reg = 0; reg < 4; reg++) {
            float rm = fmaxf(fmaxf(S[0][reg], S[1][reg]), fmaxf(S[2][reg], S[3][reg]));
            #pragma unroll
            for (int off = 1; off < 16; off <<= 1) rm = fmaxf(rm, __shfl_xor(rm, off));
            float Mn = fmaxf(M[reg], rm);
            float alpha = expc(M[reg] - Mn);
            float rs = 0.0f;
            #pragma unroll
            for (int nt = 0; nt < 4; nt++) {
                P[nt][reg] = expc(S[nt][reg] - Mn);
                rs += P[nt][reg];
            }
            #pragma unroll
            for (int off = 1; off < 16; off <<= 1) rs += __shfl_xor(rs, off);
            L[reg] = L[reg] * alpha + rs;
            M[reg] = Mn;
            #pragma unroll
            for (int nt = 0; nt < 4; nt++) O[nt][reg] *= alpha;
        }

        __syncthreads();                  // all waves done reading KP as K
        // write split P into KP buffers: [query][key]
        #pragma unroll
        for (int nt = 0; nt < 4; nt++)
            #pragma unroll
            for (int reg = 0; reg < 4; reg++) {
                bf16_t ph = f2b(P[nt][reg]);
                bf16_t pl = f2b(P[nt][reg] - b2f(ph));
                KPh[w * 16 + quad * 4 + reg][nt * 16 + l16] = ph;
                KPl[w * 16 + quad * 4 + reg][nt * 16 + l16] = pl;
            }
        __syncthreads();

        // O += P V, 3-term split.  A = P[query][key], B = V[key][dim] (from Vt)
        #pragma unroll
        for (int khf = 0; khf < 2; khf++) {
            int kb = khf * 32 + quad * 8;
            bf16x8 pH = *(const bf16x8*)&KPh[w * 16 + l16][kb];
            bf16x8 pL = *(const bf16x8*)&KPl[w * 16 + l16][kb];
            #pragma unroll
            for (int nt = 0; nt < 4; nt++) {
                bf16x8 vH = *(const bf16x8*)&Vh[nt * 16 + l16][kb];
                bf16x8 vL = *(const bf16x8*)&Vl[nt * 16 + l16][kb];
                O[nt] = mfma16(pH, vH, O[nt]);
                O[nt] = mfma16(pH, vL, O[nt]);
                O[nt] = mfma16(pL, vH, O[nt]);
            }
        }
    }

    // tail: columns [(rt+1)*64, N) all carry logit 1e-8
    int cnt = N_ - (rt + 1) * 64;
    if (cnt > 0) {
        float sv[4];
        #pragma unroll
        for (int nt = 0; nt < 4; nt++)
            sv[nt] = suff[((size_t)bh * 33 + rt + 1) * 64 + nt * 16 + l16];
        #pragma unroll
        for (int reg = 0; reg < 4; reg++) {
            float Mc = fmaxf(M[reg], MASK_C);
            float al = expc(M[reg] - Mc);
            float pc = expc(MASK_C - Mc);
            L[reg] = L[reg] * al + pc * (float)cnt;
            #pragma unroll
            for (int nt = 0; nt < 4; nt++) O[nt][reg] = O[nt][reg] * al + pc * sv[nt];
        }
    }

    #pragma unroll
    for (int reg = 0; reg < 4; reg++) {
        float rl = 1.0f / L[reg];
        int row = rt * 64 + w * 16 + quad * 4 + reg;
        #pragma unroll
        for (int nt = 0; nt < 4; nt++)
            out[((size_t)(b * N_ + row)) * DIM_ + head * 64 + nt * 16 + l16] = O[nt][reg] * rl;
    }
}

// ---------------------------------------------------------------------------
extern "C" void kernel_launch(void* const* d_in, const int* in_sizes, int n_in,
                              void* d_out, int out_size, void* d_ws, size_t ws_size,
                              hipStream_t stream) {
    const float* x     = (const float*)d_in[0];
    const float* gamma = (const float*)d_in[1];
    const float* beta  = (const float*)d_in[2];
    const float* w_qkv = (const float*)d_in[3];
    // d_in[4]: causal mask (deterministic tril) -- hardcoded in kernels.
    float* out = (float*)d_out;

    const size_t HW = (size_t)8192 * 512;     // 4.19M elems
    const size_t WN = (size_t)1536 * 512;     // 786K elems
    bf16_t* hh  = (bf16_t*)d_ws;
    bf16_t* hl  = hh + HW;
    bf16_t* qh  = hl + HW;
    bf16_t* ql  = qh + HW;
    bf16_t* kh  = ql + HW;
    bf16_t* kl  = kh + HW;
    bf16_t* vth = kl + HW;
    bf16_t* vtl = vth + HW;
    bf16_t* wh  = vtl + HW;
    bf16_t* wl  = wh + WN;
    float*  part = (float*)(wl + WN);          // 32*32*64
    float*  suff = part + (size_t)32 * 32 * 64; // 32*33*64

    ln_kernel<<<B_ * N_, 256, 0, stream>>>(x, gamma, beta, hh, hl);
    wsplit_kernel<<<768, 256, 0, stream>>>(w_qkv, wh, wl);
    qkv_gemm<<<64 * 24, 256, 0, stream>>>(hh, hl, wh, wl, qh, ql, kh, kl, vth, vtl);
    vpart_kernel<<<1024, 64, 0, stream>>>(vth, vtl, part);
    vscan_kernel<<<32, 64, 0, stream>>>(part, suff);
    attn_kernel<<<32 * 32, 256, 0, stream>>>(qh, ql, kh, kl, vth, vtl, suff, out);
}

// Round 5
// 265.278 us; speedup vs baseline: 7.9338x; 1.1544x over previous
//
#include <hip/hip_runtime.h>
#include <hip/hip_bf16.h>
#include <math.h>

// Problem constants
#define B_  4
#define N_  2048
#define DIM_ 512
#define HEADS_ 8
#define QKV_ 1536
#define MASK_C 1e-8f

typedef __bf16 bf16_t;
typedef bf16_t bf16x8 __attribute__((ext_vector_type(8)));
typedef float  f32x4  __attribute__((ext_vector_type(4)));

__device__ __forceinline__ float expc(float a) { return expf(fmaxf(a, -80.0f)); }
__device__ __forceinline__ bf16_t f2b(float x) { return (bf16_t)x; }
__device__ __forceinline__ float  b2f(bf16_t x) { return (float)x; }

__device__ __forceinline__ f32x4 mfma16(bf16x8 a, bf16x8 b, f32x4 c) {
    return __builtin_amdgcn_mfma_f32_16x16x32_bf16(a, b, c, 0, 0, 0);
}

// ---------------------------------------------------------------------------
// Kernel 1: LayerNorm -> split bf16 (h_hi, h_lo). One block per row of 512.
// ---------------------------------------------------------------------------
__global__ __launch_bounds__(256) void ln_kernel(const float* __restrict__ x,
                                                 const float* __restrict__ gamma,
                                                 const float* __restrict__ beta,
                                                 bf16_t* __restrict__ hh,
                                                 bf16_t* __restrict__ hl) {
    int row = blockIdx.x;
    int t = threadIdx.x;
    const float* xr = x + (size_t)row * DIM_;
    float e0 = xr[t];
    float e1 = xr[t + 256];
    float s  = e0 + e1;
    float sq = e0 * e0 + e1 * e1;
    for (int off = 32; off; off >>= 1) {
        s  += __shfl_xor(s, off);
        sq += __shfl_xor(sq, off);
    }
    __shared__ float red[8];
    int w = t >> 6;
    if ((t & 63) == 0) { red[w] = s; red[4 + w] = sq; }
    __syncthreads();
    float S  = red[0] + red[1] + red[2] + red[3];
    float SQ = red[4] + red[5] + red[6] + red[7];
    float mu = S * (1.0f / DIM_);
    float var = SQ * (1.0f / DIM_) - mu * mu;
    float rs = rsqrtf(var + 1e-5f);
    float y0 = (e0 - mu) * rs * gamma[t] + beta[t];
    float y1 = (e1 - mu) * rs * gamma[t + 256] + beta[t + 256];
    size_t base = (size_t)row * DIM_;
    bf16_t h0 = f2b(y0), h1 = f2b(y1);
    hh[base + t] = h0;       hl[base + t] = f2b(y0 - b2f(h0));
    hh[base + t + 256] = h1; hl[base + t + 256] = f2b(y1 - b2f(h1));
}

// ---------------------------------------------------------------------------
// Kernel 1b: split w_qkv into bf16 hi/lo.
// ---------------------------------------------------------------------------
__global__ __launch_bounds__(256) void wsplit_kernel(const float* __restrict__ w,
                                                     bf16_t* __restrict__ wh,
                                                     bf16_t* __restrict__ wl) {
    int i = (blockIdx.x * 256 + threadIdx.x) * 4;
    float4 v = *(const float4*)&w[i];
    float vv[4] = {v.x, v.y, v.z, v.w};
    #pragma unroll
    for (int j = 0; j < 4; j++) {
        bf16_t hi = f2b(vv[j]);
        wh[i + j] = hi;
        wl[i + j] = f2b(vv[j] - b2f(hi));
    }
}

// ---------------------------------------------------------------------------
// Kernel 2: QKV GEMM via MFMA, split-bf16 3-term. BK=32, LDS ~30KB (4+ blk/CU).
// Block tile 128m x 64n, 256 threads / 4 waves (wave: 32m x 64n).
// Epilogue re-splits to q/k (natural layout) and v (transposed [bh][d][key]).
// ---------------------------------------------------------------------------
__global__ __launch_bounds__(256) void qkv_gemm(const bf16_t* __restrict__ hh,
                                                const bf16_t* __restrict__ hl,
                                                const bf16_t* __restrict__ wh,
                                                const bf16_t* __restrict__ wl,
                                                bf16_t* __restrict__ qh, bf16_t* __restrict__ ql,
                                                bf16_t* __restrict__ kh, bf16_t* __restrict__ kl,
                                                bf16_t* __restrict__ vth, bf16_t* __restrict__ vtl) {
    __shared__ __align__(16) bf16_t Ah[128][40], Al[128][40];
    __shared__ __align__(16) bf16_t Bh[64][40],  Bl[64][40];
    int bm = blockIdx.x & 63;             // 64 m-tiles
    int bn = blockIdx.x >> 6;             // 24 n-tiles
    int t = threadIdx.x;
    int w = t >> 6, lane = t & 63, quad = lane >> 4, l16 = lane & 15;

    f32x4 acc[2][4];
    #pragma unroll
    for (int i = 0; i < 2; i++)
        #pragma unroll
        for (int j = 0; j < 4; j++) acc[i][j] = (f32x4)(0.0f);

    for (int k0 = 0; k0 < 512; k0 += 32) {
        __syncthreads();
        {   // stage A: thread t -> row t>>1, k-cols (t&1)*16 + {0,8}
            int m = t >> 1, kc = (t & 1) * 16;
            size_t g = (size_t)(bm * 128 + m) * 512 + k0 + kc;
            *(uint4*)&Ah[m][kc]     = *(const uint4*)&hh[g];
            *(uint4*)&Ah[m][kc + 8] = *(const uint4*)&hh[g + 8];
            *(uint4*)&Al[m][kc]     = *(const uint4*)&hl[g];
            *(uint4*)&Al[m][kc + 8] = *(const uint4*)&hl[g + 8];
            // stage B: thread t -> row t>>2, k-cols (t&3)*8
            int n = t >> 2, kc2 = (t & 3) * 8;
            size_t g2 = (size_t)(bn * 64 + n) * 512 + k0 + kc2;
            *(uint4*)&Bh[n][kc2] = *(const uint4*)&wh[g2];
            *(uint4*)&Bl[n][kc2] = *(const uint4*)&wl[g2];
        }
        __syncthreads();
        int kb = quad * 8;
        bf16x8 aH[2], aL[2];
        #pragma unroll
        for (int mt = 0; mt < 2; mt++) {
            aH[mt] = *(const bf16x8*)&Ah[w * 32 + mt * 16 + l16][kb];
            aL[mt] = *(const bf16x8*)&Al[w * 32 + mt * 16 + l16][kb];
        }
        #pragma unroll
        for (int nt = 0; nt < 4; nt++) {
            bf16x8 bH = *(const bf16x8*)&Bh[nt * 16 + l16][kb];
            bf16x8 bL = *(const bf16x8*)&Bl[nt * 16 + l16][kb];
            #pragma unroll
            for (int mt = 0; mt < 2; mt++) {
                acc[mt][nt] = mfma16(aH[mt], bH, acc[mt][nt]);
                acc[mt][nt] = mfma16(aH[mt], bL, acc[mt][nt]);
                acc[mt][nt] = mfma16(aL[mt], bH, acc[mt][nt]);
            }
        }
    }

    // epilogue: split & route. C/D layout: row = quad*4+reg, col = l16 (per tile)
    #pragma unroll
    for (int mt = 0; mt < 2; mt++)
        #pragma unroll
        for (int nt = 0; nt < 4; nt++)
            #pragma unroll
            for (int reg = 0; reg < 4; reg++) {
                float v = acc[mt][nt][reg];
                int row = bm * 128 + w * 32 + mt * 16 + quad * 4 + reg;
                int n = bn * 64 + nt * 16 + l16;
                bf16_t hi = f2b(v);
                bf16_t lo = f2b(v - b2f(hi));
                if (n < 512) {
                    size_t a = (size_t)row * 512 + n;
                    qh[a] = hi; ql[a] = lo;
                } else if (n < 1024) {
                    size_t a = (size_t)row * 512 + (n - 512);
                    kh[a] = hi; kl[a] = lo;
                } else {
                    int b = row >> 11, key = row & 2047;
                    int hd = (n - 1024) >> 6, d = (n - 1024) & 63;
                    size_t a = ((size_t)((b * 8 + hd) * 64 + d)) * 2048 + key;
                    vth[a] = hi; vtl[a] = lo;
                }
            }
}

// ---------------------------------------------------------------------------
// Kernel 3a/3b: V suffix sums (fp32, from split vt) for the masked-tail term.
// ---------------------------------------------------------------------------
__global__ void vpart_kernel(const bf16_t* __restrict__ vth,
                             const bf16_t* __restrict__ vtl,
                             float* __restrict__ part) {
    int blk = blockIdx.x;                 // 0..1023
    int bh = blk >> 5, tt = blk & 31;
    int d = threadIdx.x;                  // 0..63
    size_t base = ((size_t)(bh * 64 + d)) * 2048 + tt * 64;
    float S = 0.0f;
    #pragma unroll
    for (int k = 0; k < 64; k += 8) {
        bf16x8 a = *(const bf16x8*)&vth[base + k];
        bf16x8 c = *(const bf16x8*)&vtl[base + k];
        #pragma unroll
        for (int j = 0; j < 8; j++) S += b2f(a[j]) + b2f(c[j]);
    }
    part[((size_t)(bh * 32 + tt)) * 64 + d] = S;
}

__global__ void vscan_kernel(const float* __restrict__ part,
                             float* __restrict__ suff) {
    int bh = blockIdx.x;
    int d = threadIdx.x;
    float S = 0.0f;
    suff[((size_t)bh * 33 + 32) * 64 + d] = 0.0f;
    for (int tt = 31; tt >= 0; tt--) {
        S += part[((size_t)(bh * 32 + tt)) * 64 + d];
        suff[((size_t)bh * 33 + tt) * 64 + d] = S;
    }
}

// ---------------------------------------------------------------------------
// Kernel 4: MFMA flash attention, masked-fill=1e-8 semantics.
// QK: 3-term split-bf16 (Q frags register-resident). PV: bf16 hi only.
// L row-sums via ones-MFMA. Per-wave private P buffer -> 2 barriers/tile.
// LDS ~36.5KB -> 4 blocks/CU.
// ---------------------------------------------------------------------------
__global__ __launch_bounds__(256, 4) void attn_kernel(const bf16_t* __restrict__ qh,
                                                      const bf16_t* __restrict__ ql,
                                                      const bf16_t* __restrict__ kh,
                                                      const bf16_t* __restrict__ kl,
                                                      const bf16_t* __restrict__ vth,
                                                      const float* __restrict__ suff,
                                                      float* __restrict__ out) {
    __shared__ __align__(16) bf16_t Kh[64][72], Kl[64][72];
    __shared__ __align__(16) bf16_t Vh[64][72];               // [dim][key]
    __shared__ __align__(16) bf16_t Ps[4][16][76];            // per-wave P
    int blk = blockIdx.x;
    int bh = blk & 31;                    // interleave bh fastest
    int rt = 31 - (blk >> 5);             // longest blocks first
    int b = bh >> 3, head = bh & 7;
    int t = threadIdx.x;
    int w = t >> 6, lane = t & 63, quad = lane >> 4, l16 = lane & 15;

    // Q fragments: register-resident (wave reads only its own 16 rows)
    bf16x8 qAH[2], qAL[2];
    {
        int qrow = rt * 64 + w * 16 + l16;
        size_t g = ((size_t)(b * N_ + qrow)) * 512 + head * 64;
        qAH[0] = *(const bf16x8*)&qh[g + quad * 8];
        qAH[1] = *(const bf16x8*)&qh[g + 32 + quad * 8];
        qAL[0] = *(const bf16x8*)&ql[g + quad * 8];
        qAL[1] = *(const bf16x8*)&ql[g + 32 + quad * 8];
    }
    bf16x8 ones;
    #pragma unroll
    for (int j = 0; j < 8; j++) ones[j] = f2b(1.0f);

    f32x4 O[4];
    #pragma unroll
    for (int nt = 0; nt < 4; nt++) O[nt] = (f32x4)(0.0f);
    float M[4], L[4];
    #pragma unroll
    for (int r = 0; r < 4; r++) { M[r] = -3.0e38f; L[r] = 0.0f; }

    for (int jt = 0; jt <= rt; jt++) {
        __syncthreads();                  // all waves done with prev K/V
        {   // stage K (hi+lo) and V (hi, [dim][key] source)
            int r = t >> 2, c = (t & 3) * 16;
            size_t gk = ((size_t)(b * N_ + jt * 64 + r)) * 512 + head * 64 + c;
            *(uint4*)&Kh[r][c]     = *(const uint4*)&kh[gk];
            *(uint4*)&Kh[r][c + 8] = *(const uint4*)&kh[gk + 8];
            *(uint4*)&Kl[r][c]     = *(const uint4*)&kl[gk];
            *(uint4*)&Kl[r][c + 8] = *(const uint4*)&kl[gk + 8];
            size_t gv = ((size_t)(bh * 64 + r)) * 2048 + jt * 64 + c;  // r=dim, c=key
            *(uint4*)&Vh[r][c]     = *(const uint4*)&vth[gv];
            *(uint4*)&Vh[r][c + 8] = *(const uint4*)&vth[gv + 8];
        }
        __syncthreads();

        // S = Q K^T, 3-term split
        f32x4 S[4];
        #pragma unroll
        for (int nt = 0; nt < 4; nt++) S[nt] = (f32x4)(0.0f);
        #pragma unroll
        for (int khf = 0; khf < 2; khf++) {
            int kb = khf * 32 + quad * 8;
            #pragma unroll
            for (int nt = 0; nt < 4; nt++) {
                bf16x8 bH = *(const bf16x8*)&Kh[nt * 16 + l16][kb];
                bf16x8 bL = *(const bf16x8*)&Kl[nt * 16 + l16][kb];
                S[nt] = mfma16(qAH[khf], bH, S[nt]);
                S[nt] = mfma16(qAH[khf], bL, S[nt]);
                S[nt] = mfma16(qAL[khf], bH, S[nt]);
            }
        }

        // diagonal-tile causal mask: logit := 1e-8 where col > row (local)
        if (jt == rt) {
            int lrow = w * 16 + quad * 4;
            #pragma unroll
            for (int nt = 0; nt < 4; nt++)
                #pragma unroll
                for (int reg = 0; reg < 4; reg++)
                    if (nt * 16 + l16 > lrow + reg) S[nt][reg] = MASK_C;
        }

        // online max per row (row = quad*4+reg; reduce across the 16 l16 lanes)
        float alpha[4];
        #pragma unroll
        for (int reg = 0; reg < 4; reg++) {
            float rm = fmaxf(fmaxf(S[0][reg], S[1][reg]), fmaxf(S[2][reg], S[3][reg]));
            #pragma unroll
            for (int off = 1; off < 16; off <<= 1) rm = fmaxf(rm, __shfl_xor(rm, off));
            float Mn = fmaxf(M[reg], rm);
            alpha[reg] = expc(M[reg] - Mn);
            M[reg] = Mn;
            #pragma unroll
            for (int nt = 0; nt < 4; nt++) O[nt][reg] *= alpha[reg];
        }

        // P = exp(S - M), write own wave's rows into private Ps (bf16 hi only)
        #pragma unroll
        for (int nt = 0; nt < 4; nt++)
            #pragma unroll
            for (int reg = 0; reg < 4; reg++)
                Ps[w][quad * 4 + reg][nt * 16 + l16] = f2b(expc(S[nt][reg] - M[reg]));
        // (same-wave DS ops are in program order; no barrier needed for Ps)

        bf16x8 pH[2];
        #pragma unroll
        for (int khf = 0; khf < 2; khf++)
            pH[khf] = *(const bf16x8*)&Ps[w][l16][khf * 32 + quad * 8];

        // L row-sums via ones-MFMA (every lane receives the row sum)
        f32x4 Lx = (f32x4)(0.0f);
        #pragma unroll
        for (int khf = 0; khf < 2; khf++) Lx = mfma16(pH[khf], ones, Lx);
        #pragma unroll
        for (int reg = 0; reg < 4; reg++) L[reg] = L[reg] * alpha[reg] + Lx[reg];

        // O += P V  (A = P[q][key], B = V[dim][key])
        #pragma unroll
        for (int khf = 0; khf < 2; khf++) {
            int kb = khf * 32 + quad * 8;
            #pragma unroll
            for (int nt = 0; nt < 4; nt++) {
                bf16x8 vB = *(const bf16x8*)&Vh[nt * 16 + l16][kb];
                O[nt] = mfma16(pH[khf], vB, O[nt]);
            }
        }
    }

    // tail: columns [(rt+1)*64, N) all carry logit 1e-8
    int cnt = N_ - (rt + 1) * 64;
    if (cnt > 0) {
        float sv[4];
        #pragma unroll
        for (int nt = 0; nt < 4; nt++)
            sv[nt] = suff[((size_t)bh * 33 + rt + 1) * 64 + nt * 16 + l16];
        #pragma unroll
        for (int reg = 0; reg < 4; reg++) {
            float Mc = fmaxf(M[reg], MASK_C);
            float al = expc(M[reg] - Mc);
            float pc = expc(MASK_C - Mc);
            L[reg] = L[reg] * al + pc * (float)cnt;
            #pragma unroll
            for (int nt = 0; nt < 4; nt++) O[nt][reg] = O[nt][reg] * al + pc * sv[nt];
        }
    }

    #pragma unroll
    for (int reg = 0; reg < 4; reg++) {
        float rl = 1.0f / L[reg];
        int row = rt * 64 + w * 16 + quad * 4 + reg;
        #pragma unroll
        for (int nt = 0; nt < 4; nt++)
            out[((size_t)(b * N_ + row)) * DIM_ + head * 64 + nt * 16 + l16] = O[nt][reg] * rl;
    }
}

// ---------------------------------------------------------------------------
extern "C" void kernel_launch(void* const* d_in, const int* in_sizes, int n_in,
                              void* d_out, int out_size, void* d_ws, size_t ws_size,
                              hipStream_t stream) {
    const float* x     = (const float*)d_in[0];
    const float* gamma = (const float*)d_in[1];
    const float* beta  = (const float*)d_in[2];
    const float* w_qkv = (const float*)d_in[3];
    // d_in[4]: causal mask (deterministic tril) -- hardcoded in kernels.
    float* out = (float*)d_out;

    const size_t HW = (size_t)8192 * 512;
    const size_t WN = (size_t)1536 * 512;
    bf16_t* hh  = (bf16_t*)d_ws;
    bf16_t* hl  = hh + HW;
    bf16_t* qh  = hl + HW;
    bf16_t* ql  = qh + HW;
    bf16_t* kh  = ql + HW;
    bf16_t* kl  = kh + HW;
    bf16_t* vth = kl + HW;
    bf16_t* vtl = vth + HW;
    bf16_t* wh  = vtl + HW;
    bf16_t* wl  = wh + WN;
    float*  part = (float*)(wl + WN);
    float*  suff = part + (size_t)32 * 32 * 64;

    ln_kernel<<<B_ * N_, 256, 0, stream>>>(x, gamma, beta, hh, hl);
    wsplit_kernel<<<768, 256, 0, stream>>>(w_qkv, wh, wl);
    qkv_gemm<<<64 * 24, 256, 0, stream>>>(hh, hl, wh, wl, qh, ql, kh, kl, vth, vtl);
    vpart_kernel<<<1024, 64, 0, stream>>>(vth, vtl, part);
    vscan_kernel<<<32, 64, 0, stream>>>(part, suff);
    attn_kernel<<<1024, 256, 0, stream>>>(qh, ql, kh, kl, vth, suff, out);
}